// Round 2
// baseline (19548.936 us; speedup 1.0000x reference)
//
#include <hip/hip_runtime.h>
#include <hip/hip_cooperative_groups.h>

namespace cg = cooperative_groups;

typedef short short8 __attribute__((ext_vector_type(8)));
typedef float f32x4 __attribute__((ext_vector_type(4)));

#define T_LEN 512
#define BATCH 64
#define DIN   512
#define HID   1024
#define KTOT  1536   // DIN + HID

__device__ __forceinline__ unsigned short f2bf(float x) {
    unsigned int u = __builtin_bit_cast(unsigned int, x);
    unsigned int r = (u + 0x7fffu + ((u >> 16) & 1u)) >> 16;
    return (unsigned short)r;
}

// ---- Kernel 1: transpose+convert [Wx;Wh] (1536 x 4096 f32) -> W_T (4096 x 1536 bf16)
__global__ void wtrans_kernel(const float* __restrict__ Wx, const float* __restrict__ Wh,
                              unsigned short* __restrict__ W_T) {
    __shared__ float tile[32][33];
    int tx = threadIdx.x, ty = threadIdx.y;
    int k0 = blockIdx.x * 32, c0 = blockIdx.y * 32;
    for (int i = 0; i < 32; i += 8) {
        int k = k0 + ty + i;
        int c = c0 + tx;
        float v = (k < DIN) ? Wx[(size_t)k * 4096 + c] : Wh[(size_t)(k - DIN) * 4096 + c];
        tile[ty + i][tx] = v;
    }
    __syncthreads();
    for (int i = 0; i < 32; i += 8) {
        int c = c0 + ty + i;
        int k = k0 + tx;
        W_T[(size_t)c * KTOT + k] = f2bf(tile[tx][ty + i]);
    }
}

// ---- Kernel 2: x [B][T][D] f32 -> x_tbd [T][B][D] bf16
__global__ void xtrans_kernel(const float* __restrict__ x, unsigned short* __restrict__ x_tbd) {
    int idx = blockIdx.x * 256 + threadIdx.x;   // 4,194,304 items of 4 elements
    int d4 = idx & 127;                         // 512/4
    int bt = idx >> 7;
    int t = bt & (T_LEN - 1);
    int b = bt >> 9;
    const float4 v = *reinterpret_cast<const float4*>(x + (((size_t)b * T_LEN + t) * DIN + d4 * 4));
    ushort4 o;
    o.x = f2bf(v.x); o.y = f2bf(v.y); o.z = f2bf(v.z); o.w = f2bf(v.w);
    *reinterpret_cast<ushort4*>(x_tbd + (((size_t)t * BATCH + b) * DIN + d4 * 4)) = o;
}

// ---- Kernel 3: zero h-buffer 0, build bias = bx + bh
__global__ void init_kernel(const float* __restrict__ bx, const float* __restrict__ bh,
                            unsigned short* __restrict__ hbuf, float* __restrict__ bias) {
    int i = blockIdx.x * 256 + threadIdx.x;     // 32768 threads
    if (i < (BATCH * HID) / 2) ((unsigned int*)hbuf)[i] = 0u;  // zero buffer 0 (128 KB)
    if (i < 4096) bias[i] = bx[i] + bh[i];
}

// ---- Kernel 4: persistent cooperative LSTM
// grid = 256 WGs x 256 threads. WG = (batch-group bg in {0,1}) x (unit-group ug in 0..127).
// Each WG owns 8 hidden units (32 gate cols), weights slice resident in LDS.
__global__ void __launch_bounds__(256, 1)
lstm_kernel(const unsigned short* __restrict__ x_tbd, const unsigned short* __restrict__ W_T,
            const float* __restrict__ bias, const int* __restrict__ lengths,
            unsigned short* __restrict__ hbuf, float* __restrict__ out) {
    __shared__ unsigned short BW[32][1544];   // [n][k], pad 8 elems (16B) vs 1536
    __shared__ float gates[32][33];
    __shared__ float biass[32];

    cg::grid_group grid = cg::this_grid();

    const int tid = threadIdx.x;
    const int wg = blockIdx.x;
    const int bg = wg >> 7;      // 0..1  -> batches [bg*32, bg*32+32)
    const int ug = wg & 127;     // 0..127 -> units [ug*8, ug*8+8)

    // ---- one-time: stage weight slice into LDS (cols ordered i(u0..7),f,o,g)
    {
        const int n = tid >> 3, t8 = tid & 7;
        const int gam = n >> 3, uu = n & 7;
        const size_t col = (size_t)(gam * HID + ug * 8 + uu);
        const unsigned short* src = W_T + col * KTOT;
        for (int j = 0; j < 24; ++j) {
            int k = t8 * 192 + j * 8;
            *reinterpret_cast<short8*>(&BW[n][k]) =
                *reinterpret_cast<const short8*>(src + k);
        }
        if (tid < 32) {
            int gam2 = tid >> 3, u2 = tid & 7;
            biass[tid] = bias[gam2 * HID + ug * 8 + u2];
        }
    }

    // ---- per-thread elementwise state: thread <-> (batch m_loc, unit u)
    const int m_loc = tid >> 3, u = tid & 7;
    const int b = bg * 32 + m_loc;
    const int unit = ug * 8 + u;
    const int len = lengths[b];
    float h = 0.f, c = 0.f;

    // ---- wave mapping for MFMA: wave (mi, ni) owns 16 batches x 16 gate cols
    const int wv = tid >> 6, lane = tid & 63;
    const int mi = wv & 1, ni = wv >> 1;
    const int m16 = lane & 15, kb = lane >> 4;
    const int arow = bg * 32 + mi * 16 + m16;                    // global batch row for A-frag
    const unsigned short* bwrow = &BW[ni * 16 + m16][kb * 8];    // B-frag: col = lane&15, k_local = kb*8+{0..7}

    __syncthreads();   // BW + biass ready

    for (int t = 0; t < T_LEN; ++t) {
        const unsigned short* hcur = hbuf + (size_t)(t & 1) * (BATCH * HID);
        unsigned short* hnxt = hbuf + (size_t)((t + 1) & 1) * (BATCH * HID);

        f32x4 acc = {0.f, 0.f, 0.f, 0.f};
        const unsigned short* xa = x_tbd + ((size_t)t * BATCH + arow) * DIN + kb * 8;
        const unsigned short* ha = hcur + (size_t)arow * HID + kb * 8;

#pragma unroll
        for (int ks = 0; ks < 16; ++ks) {   // x_t part: k = 0..511
            short8 af = *reinterpret_cast<const short8*>(xa + ks * 32);
            short8 bf = *reinterpret_cast<const short8*>(bwrow + ks * 32);
            acc = __builtin_amdgcn_mfma_f32_16x16x32_bf16(af, bf, acc, 0, 0, 0);
        }
#pragma unroll
        for (int kh = 0; kh < 32; ++kh) {   // h part: k = 512..1535
            short8 af = *reinterpret_cast<const short8*>(ha + kh * 32);
            short8 bf = *reinterpret_cast<const short8*>(bwrow + (16 + kh) * 32);
            acc = __builtin_amdgcn_mfma_f32_16x16x32_bf16(af, bf, acc, 0, 0, 0);
        }

        // C/D layout (m89): col = lane&15, row = (lane>>4)*4 + reg
        {
            const int grow = mi * 16 + kb * 4;
            const int gcol = ni * 16 + m16;
            gates[grow + 0][gcol] = acc[0];
            gates[grow + 1][gcol] = acc[1];
            gates[grow + 2][gcol] = acc[2];
            gates[grow + 3][gcol] = acc[3];
        }
        __syncthreads();

        // ---- elementwise LSTM cell for this thread's (b, unit)
        {
            float gi = gates[m_loc][u]      + biass[u];
            float gf = gates[m_loc][8 + u]  + biass[8 + u];
            float go = gates[m_loc][16 + u] + biass[16 + u];
            float gg = gates[m_loc][24 + u] + biass[24 + u];
            float si = 1.f / (1.f + __expf(-gi));
            float sf = 1.f / (1.f + __expf(-gf));
            float so = 1.f / (1.f + __expf(-go));
            float tg = 1.f - 2.f / (__expf(2.f * gg) + 1.f);
            float cc = sf * c + si * tg;
            float hc = so * (1.f - 2.f / (__expf(2.f * cc) + 1.f));
            if (t < len) { c = cc; h = hc; }
            out[((size_t)b * T_LEN + t) * HID + unit] = h;
            hnxt[(size_t)b * HID + unit] = f2bf(h);   // carried value even when masked
        }
        grid.sync();
    }

    // final states: out = [seq (B,T,H) | h_t (B,H) | c_t (B,H)]
    const size_t base = (size_t)BATCH * T_LEN * HID;
    out[base + (size_t)b * HID + unit] = h;
    out[base + (size_t)BATCH * HID + (size_t)b * HID + unit] = c;
}

extern "C" void kernel_launch(void* const* d_in, const int* in_sizes, int n_in,
                              void* d_out, int out_size, void* d_ws, size_t ws_size,
                              hipStream_t stream) {
    const float* x       = (const float*)d_in[0];
    const int*   lengths = (const int*)d_in[1];
    const float* Wx      = (const float*)d_in[2];
    const float* bx      = (const float*)d_in[3];
    const float* Wh      = (const float*)d_in[4];
    const float* bh      = (const float*)d_in[5];
    float* out = (float*)d_out;

    unsigned char* ws = (unsigned char*)d_ws;
    unsigned short* W_T   = (unsigned short*)(ws);                       // 4096*1536*2 = 12,582,912 B
    unsigned short* x_tbd = (unsigned short*)(ws + 12582912);            // 512*64*512*2 = 33,554,432 B
    unsigned short* hbuf  = (unsigned short*)(ws + 12582912 + 33554432); // 2*64*1024*2 = 262,144 B
    float*          bias  = (float*)(ws + 12582912 + 33554432 + 262144); // 4096*4 B

    wtrans_kernel<<<dim3(KTOT / 32, 4096 / 32), dim3(32, 8), 0, stream>>>(Wx, Wh, W_T);
    xtrans_kernel<<<16384, 256, 0, stream>>>(x, x_tbd);
    init_kernel<<<128, 256, 0, stream>>>(bx, bh, hbuf, bias);

    void* args[] = {(void*)&x_tbd, (void*)&W_T, (void*)&bias, (void*)&lengths,
                    (void*)&hbuf, (void*)&out};
    hipLaunchCooperativeKernel((void*)lstm_kernel, dim3(256), dim3(256), args, 0, stream);
}

// Round 3
// 6038.176 us; speedup vs baseline: 3.2376x; 3.2376x over previous
//
#include <hip/hip_runtime.h>

typedef short short8 __attribute__((ext_vector_type(8)));
typedef short short4v __attribute__((ext_vector_type(4)));
typedef float f32x4 __attribute__((ext_vector_type(4)));

#define T_LEN 512
#define BATCH 64
#define DIN   512
#define HID   1024
#define KTOT  1536   // DIN + HID
#define NWG   256

__device__ __forceinline__ unsigned short f2bf(float x) {
    unsigned int u = __builtin_bit_cast(unsigned int, x);
    unsigned int r = (u + 0x7fffu + ((u >> 16) & 1u)) >> 16;
    return (unsigned short)r;
}

// coherent (agent-scope, L2-bypassing) 8B h-fragment helpers
__device__ __forceinline__ short8 ld_h_frag(const unsigned short* p) {
    unsigned long long lo = __hip_atomic_load((const unsigned long long*)p,
                                              __ATOMIC_RELAXED, __HIP_MEMORY_SCOPE_AGENT);
    unsigned long long hi = __hip_atomic_load((const unsigned long long*)(p + 4),
                                              __ATOMIC_RELAXED, __HIP_MEMORY_SCOPE_AGENT);
    short4v a = __builtin_bit_cast(short4v, lo);
    short4v b = __builtin_bit_cast(short4v, hi);
    short8 r = {a[0], a[1], a[2], a[3], b[0], b[1], b[2], b[3]};
    return r;
}

// ---- Kernel 1: transpose+convert [Wx;Wh] (1536 x 4096 f32) -> W_T (4096 x 1536 bf16)
__global__ void wtrans_kernel(const float* __restrict__ Wx, const float* __restrict__ Wh,
                              unsigned short* __restrict__ W_T) {
    __shared__ float tile[32][33];
    int tx = threadIdx.x, ty = threadIdx.y;
    int k0 = blockIdx.x * 32, c0 = blockIdx.y * 32;
    for (int i = 0; i < 32; i += 8) {
        int k = k0 + ty + i;
        int c = c0 + tx;
        float v = (k < DIN) ? Wx[(size_t)k * 4096 + c] : Wh[(size_t)(k - DIN) * 4096 + c];
        tile[ty + i][tx] = v;
    }
    __syncthreads();
    for (int i = 0; i < 32; i += 8) {
        int c = c0 + ty + i;
        int k = k0 + tx;
        W_T[(size_t)c * KTOT + k] = f2bf(tile[tx][ty + i]);
    }
}

// ---- Kernel 2: x [B][T][D] f32 -> x_tbd [T][B][D] bf16
__global__ void xtrans_kernel(const float* __restrict__ x, unsigned short* __restrict__ x_tbd) {
    int idx = blockIdx.x * 256 + threadIdx.x;   // 4,194,304 items of 4 elements
    int d4 = idx & 127;                         // 512/4
    int bt = idx >> 7;
    int t = bt & (T_LEN - 1);
    int b = bt >> 9;
    const float4 v = *reinterpret_cast<const float4*>(x + (((size_t)b * T_LEN + t) * DIN + d4 * 4));
    ushort4 o;
    o.x = f2bf(v.x); o.y = f2bf(v.y); o.z = f2bf(v.z); o.w = f2bf(v.w);
    *reinterpret_cast<ushort4*>(x_tbd + (((size_t)t * BATCH + b) * DIN + d4 * 4)) = o;
}

// ---- Kernel 3: zero h-buffer 0 + barrier counter, build bias = bx + bh
__global__ void init_kernel(const float* __restrict__ bx, const float* __restrict__ bh,
                            unsigned short* __restrict__ hbuf, float* __restrict__ bias,
                            unsigned int* __restrict__ ctr) {
    int i = blockIdx.x * 256 + threadIdx.x;     // 32768 threads
    if (i < (BATCH * HID) / 2) ((unsigned int*)hbuf)[i] = 0u;  // zero buffer 0 (128 KB)
    if (i < 4096) bias[i] = bx[i] + bh[i];
    if (i == 0) *ctr = 0u;
}

// ---- Kernel 4: persistent LSTM with hand-rolled fence-free grid barrier
// grid = 256 WGs x 256 threads. WG = (batch-group bg in {0,1}) x (unit-group ug in 0..127).
__global__ void __launch_bounds__(256, 1)
lstm_kernel(const unsigned short* __restrict__ x_tbd, const unsigned short* __restrict__ W_T,
            const float* __restrict__ bias, const int* __restrict__ lengths,
            unsigned short* __restrict__ hbuf, float* __restrict__ out,
            unsigned int* __restrict__ ctr) {
    __shared__ unsigned short BW[32][1544];   // [n][k], pad 8 elems (16B) vs 1536
    __shared__ float gates[32][33];
    __shared__ float biass[32];
    __shared__ unsigned short hsh[32][8];

    const int tid = threadIdx.x;
    const int wg = blockIdx.x;
    const int bg = wg >> 7;      // 0..1  -> batches [bg*32, bg*32+32)
    const int ug = wg & 127;     // 0..127 -> units [ug*8, ug*8+8)

    // ---- one-time: stage weight slice into LDS (cols ordered i(u0..7),f,o,g)
    {
        const int n = tid >> 3, t8 = tid & 7;
        const int gam = n >> 3, uu = n & 7;
        const size_t col = (size_t)(gam * HID + ug * 8 + uu);
        const unsigned short* src = W_T + col * KTOT;
        for (int j = 0; j < 24; ++j) {
            int k = t8 * 192 + j * 8;
            *reinterpret_cast<short8*>(&BW[n][k]) =
                *reinterpret_cast<const short8*>(src + k);
        }
        if (tid < 32) {
            int gam2 = tid >> 3, u2 = tid & 7;
            biass[tid] = bias[gam2 * HID + ug * 8 + u2];
        }
    }

    // ---- per-thread elementwise state: thread <-> (batch m_loc, unit u)
    const int m_loc = tid >> 3, u = tid & 7;
    const int b = bg * 32 + m_loc;
    const int unit = ug * 8 + u;
    const int len = lengths[b];
    float h = 0.f, c = 0.f;

    // ---- wave mapping for MFMA: wave (mi, ni) owns 16 batches x 16 gate cols
    const int wv = tid >> 6, lane = tid & 63;
    const int mi = wv & 1, ni = wv >> 1;
    const int m16 = lane & 15, kb = lane >> 4;
    const int arow = bg * 32 + mi * 16 + m16;                    // global batch row for A-frag
    const unsigned short* bwrow = &BW[ni * 16 + m16][kb * 8];    // B-frag: col = lane&15, k_local = kb*8+{0..7}

    __syncthreads();   // BW + biass ready

    for (int t = 0; t < T_LEN; ++t) {
        const unsigned short* hcur = hbuf + (size_t)(t & 1) * (BATCH * HID);
        unsigned short* hnxt = hbuf + (size_t)((t + 1) & 1) * (BATCH * HID);

        // ---- x-part first: independent of h_t, runs before the barrier wait
        f32x4 acc = {0.f, 0.f, 0.f, 0.f};
        const unsigned short* xa = x_tbd + ((size_t)t * BATCH + arow) * DIN + kb * 8;
#pragma unroll
        for (int ks = 0; ks < 16; ++ks) {   // x_t part: k = 0..511
            short8 af = *reinterpret_cast<const short8*>(xa + ks * 32);
            short8 bf = *reinterpret_cast<const short8*>(bwrow + ks * 32);
            acc = __builtin_amdgcn_mfma_f32_16x16x32_bf16(af, bf, acc, 0, 0, 0);
        }

        // ---- fence-free grid barrier: wait until all WGs published h_t
        if (t > 0 && tid == 0) {
            const unsigned int target = (unsigned int)NWG * (unsigned int)t;
            while (__hip_atomic_load(ctr, __ATOMIC_RELAXED, __HIP_MEMORY_SCOPE_AGENT) < target)
                __builtin_amdgcn_s_sleep(1);
        }
        __syncthreads();

        // ---- h-part: coherent loads straight from the coherence point
        const unsigned short* ha = hcur + (size_t)arow * HID + kb * 8;
#pragma unroll
        for (int kh = 0; kh < 32; ++kh) {   // h part: k = 512..1535
            short8 af = ld_h_frag(ha + kh * 32);
            short8 bf = *reinterpret_cast<const short8*>(bwrow + (16 + kh) * 32);
            acc = __builtin_amdgcn_mfma_f32_16x16x32_bf16(af, bf, acc, 0, 0, 0);
        }

        // C/D layout (m89): col = lane&15, row = (lane>>4)*4 + reg
        {
            const int grow = mi * 16 + kb * 4;
            const int gcol = ni * 16 + m16;
            gates[grow + 0][gcol] = acc[0];
            gates[grow + 1][gcol] = acc[1];
            gates[grow + 2][gcol] = acc[2];
            gates[grow + 3][gcol] = acc[3];
        }
        __syncthreads();   // (A) gates ready

        // ---- elementwise LSTM cell for this thread's (b, unit)
        {
            float gi = gates[m_loc][u]      + biass[u];
            float gf = gates[m_loc][8 + u]  + biass[8 + u];
            float go = gates[m_loc][16 + u] + biass[16 + u];
            float gg = gates[m_loc][24 + u] + biass[24 + u];
            float si = 1.f / (1.f + __expf(-gi));
            float sf = 1.f / (1.f + __expf(-gf));
            float so = 1.f / (1.f + __expf(-go));
            float tg = 1.f - 2.f / (__expf(2.f * gg) + 1.f);
            float cc = sf * c + si * tg;
            float hc = so * (1.f - 2.f / (__expf(2.f * cc) + 1.f));
            if (t < len) { c = cc; h = hc; }
            out[((size_t)b * T_LEN + t) * HID + unit] = h;
            hsh[m_loc][u] = f2bf(h);       // carried value even when masked
        }
        __syncthreads();   // (B) hsh ready

        // ---- publish h_{t+1}: packed 8B agent-scope atomic stores (64 per WG)
        if (tid < 64) {
            const int ml = tid >> 1, q = tid & 1;
            unsigned long long v =
                  (unsigned long long)hsh[ml][q * 4 + 0]
                | ((unsigned long long)hsh[ml][q * 4 + 1] << 16)
                | ((unsigned long long)hsh[ml][q * 4 + 2] << 32)
                | ((unsigned long long)hsh[ml][q * 4 + 3] << 48);
            const int bglob = bg * 32 + ml;
            __hip_atomic_store((unsigned long long*)(hnxt + (size_t)bglob * HID + ug * 8 + q * 4), v,
                               __ATOMIC_RELAXED, __HIP_MEMORY_SCOPE_AGENT);
        }
        asm volatile("s_waitcnt vmcnt(0)" ::: "memory");   // h stores acknowledged at coherence point
        __syncthreads();   // (C) every wave's stores are done
        if (tid == 0)
            __hip_atomic_fetch_add(ctr, 1u, __ATOMIC_RELAXED, __HIP_MEMORY_SCOPE_AGENT);
    }

    // final states: out = [seq (B,T,H) | h_t (B,H) | c_t (B,H)]
    const size_t base = (size_t)BATCH * T_LEN * HID;
    out[base + (size_t)b * HID + unit] = h;
    out[base + (size_t)BATCH * HID + (size_t)b * HID + unit] = c;
}

extern "C" void kernel_launch(void* const* d_in, const int* in_sizes, int n_in,
                              void* d_out, int out_size, void* d_ws, size_t ws_size,
                              hipStream_t stream) {
    const float* x       = (const float*)d_in[0];
    const int*   lengths = (const int*)d_in[1];
    const float* Wx      = (const float*)d_in[2];
    const float* bx      = (const float*)d_in[3];
    const float* Wh      = (const float*)d_in[4];
    const float* bh      = (const float*)d_in[5];
    float* out = (float*)d_out;

    unsigned char* ws = (unsigned char*)d_ws;
    unsigned short* W_T   = (unsigned short*)(ws);                       // 12,582,912 B
    unsigned short* x_tbd = (unsigned short*)(ws + 12582912);            // 33,554,432 B
    unsigned short* hbuf  = (unsigned short*)(ws + 12582912 + 33554432); // 262,144 B
    float*          bias  = (float*)(ws + 46137344 + 262144);            // 16,384 B
    unsigned int*   ctr   = (unsigned int*)(ws + 46137344 + 262144 + 16384);

    wtrans_kernel<<<dim3(KTOT / 32, 4096 / 32), dim3(32, 8), 0, stream>>>(Wx, Wh, W_T);
    xtrans_kernel<<<16384, 256, 0, stream>>>(x, x_tbd);
    init_kernel<<<128, 256, 0, stream>>>(bx, bh, hbuf, bias, ctr);

    void* args[] = {(void*)&x_tbd, (void*)&W_T, (void*)&bias, (void*)&lengths,
                    (void*)&hbuf, (void*)&out, (void*)&ctr};
    hipLaunchCooperativeKernel((void*)lstm_kernel, dim3(256), dim3(256), args, 0, stream);
}

// Round 4
// 3442.953 us; speedup vs baseline: 5.6780x; 1.7538x over previous
//
#include <hip/hip_runtime.h>

typedef short short8 __attribute__((ext_vector_type(8)));
typedef short short4v __attribute__((ext_vector_type(4)));
typedef float f32x4 __attribute__((ext_vector_type(4)));

#define T_LEN 512
#define BATCH 64
#define DIN   512
#define HID   1024
#define KTOT  1536   // DIN + HID
#define NWG   256

__device__ __forceinline__ unsigned short f2bf(float x) {
    unsigned int u = __builtin_bit_cast(unsigned int, x);
    unsigned int r = (u + 0x7fffu + ((u >> 16) & 1u)) >> 16;
    return (unsigned short)r;
}

// coherent (agent-scope, MALL-direct) 16B h-fragment load as 2x8B
__device__ __forceinline__ short8 ld_h_frag(const unsigned short* p) {
    unsigned long long lo = __hip_atomic_load((const unsigned long long*)p,
                                              __ATOMIC_RELAXED, __HIP_MEMORY_SCOPE_AGENT);
    unsigned long long hi = __hip_atomic_load((const unsigned long long*)(p + 4),
                                              __ATOMIC_RELAXED, __HIP_MEMORY_SCOPE_AGENT);
    short4v a = __builtin_bit_cast(short4v, lo);
    short4v b = __builtin_bit_cast(short4v, hi);
    short8 r = {a[0], a[1], a[2], a[3], b[0], b[1], b[2], b[3]};
    return r;
}

// ---- Kernel 1: transpose+convert [Wx;Wh] (1536 x 4096 f32) -> W_T (4096 x 1536 bf16)
__global__ void wtrans_kernel(const float* __restrict__ Wx, const float* __restrict__ Wh,
                              unsigned short* __restrict__ W_T) {
    __shared__ float tile[32][33];
    int tx = threadIdx.x, ty = threadIdx.y;
    int k0 = blockIdx.x * 32, c0 = blockIdx.y * 32;
    for (int i = 0; i < 32; i += 8) {
        int k = k0 + ty + i;
        int c = c0 + tx;
        float v = (k < DIN) ? Wx[(size_t)k * 4096 + c] : Wh[(size_t)(k - DIN) * 4096 + c];
        tile[ty + i][tx] = v;
    }
    __syncthreads();
    for (int i = 0; i < 32; i += 8) {
        int c = c0 + ty + i;
        int k = k0 + tx;
        W_T[(size_t)c * KTOT + k] = f2bf(tile[tx][ty + i]);
    }
}

// ---- Kernel 2: x [B][T][D] f32 -> x_tbd [T][B][D] bf16
__global__ void xtrans_kernel(const float* __restrict__ x, unsigned short* __restrict__ x_tbd) {
    int idx = blockIdx.x * 256 + threadIdx.x;   // 4,194,304 items of 4 elements
    int d4 = idx & 127;                         // 512/4
    int bt = idx >> 7;
    int t = bt & (T_LEN - 1);
    int b = bt >> 9;
    const float4 v = *reinterpret_cast<const float4*>(x + (((size_t)b * T_LEN + t) * DIN + d4 * 4));
    ushort4 o;
    o.x = f2bf(v.x); o.y = f2bf(v.y); o.z = f2bf(v.z); o.w = f2bf(v.w);
    *reinterpret_cast<ushort4*>(x_tbd + (((size_t)t * BATCH + b) * DIN + d4 * 4)) = o;
}

// ---- Kernel 3: zero h-buffer 0 + arrival slots, build bias = bx + bh
__global__ void init_kernel(const float* __restrict__ bx, const float* __restrict__ bh,
                            unsigned short* __restrict__ hbuf, float* __restrict__ bias,
                            unsigned int* __restrict__ slots) {
    int i = blockIdx.x * 256 + threadIdx.x;     // 32768 threads
    if (i < (BATCH * HID) / 2) ((unsigned int*)hbuf)[i] = 0u;  // zero buffer 0 (128 KB)
    if (i < 4096) bias[i] = bx[i] + bh[i];
    if (i < NWG) slots[i] = 0u;
}

// ---- Kernel 4: persistent LSTM, slot barrier + k-split waves
// grid = 256 WGs x 256 threads. WG = (bg in {0,1}) x (ug in 0..127) -> 32 batches x 8 units.
// Waves (mi, ks): mi = M-half (16 rows), ks = k-half; each wave computes BOTH ni tiles.
__global__ void __launch_bounds__(256, 1)
lstm_kernel(const unsigned short* __restrict__ x_tbd, const unsigned short* __restrict__ W_T,
            const float* __restrict__ bias, const int* __restrict__ lengths,
            unsigned short* __restrict__ hbuf, float* __restrict__ out,
            unsigned int* __restrict__ slots) {
    __shared__ unsigned short BW[32][1544];   // [n][k], pad 8 elems (16B)
    __shared__ float gatesP[2][32][33];       // partial gates per k-half
    __shared__ float biass[32];
    __shared__ unsigned short hsh[32][8];
    __shared__ unsigned int ldsflag;

    const int tid = threadIdx.x;
    const int wg = blockIdx.x;
    const int bg = wg >> 7;      // 0..1  -> batches [bg*32, bg*32+32)
    const int ug = wg & 127;     // 0..127 -> units [ug*8, ug*8+8)

    if (tid == 0) ldsflag = 0u;

    // ---- one-time: stage weight slice into LDS (col n = gate(n>>3), unit(n&7))
    {
        const int n = tid >> 3, t8 = tid & 7;
        const int gam = n >> 3, uu = n & 7;
        const size_t col = (size_t)(gam * HID + ug * 8 + uu);
        const unsigned short* src = W_T + col * KTOT;
        for (int j = 0; j < 24; ++j) {
            int k = t8 * 192 + j * 8;
            *reinterpret_cast<short8*>(&BW[n][k]) =
                *reinterpret_cast<const short8*>(src + k);
        }
        if (tid < 32) {
            int gam2 = tid >> 3, u2 = tid & 7;
            biass[tid] = bias[gam2 * HID + ug * 8 + u2];
        }
    }

    // ---- per-thread elementwise state: thread <-> (batch m_loc, unit u)
    const int m_loc = tid >> 3, u = tid & 7;
    const int b = bg * 32 + m_loc;
    const int unit = ug * 8 + u;
    const int len = lengths[b];
    float h = 0.f, c = 0.f;

    // ---- wave mapping: wave wv -> (mi = wv&1, ks = wv>>1)
    const int wv = tid >> 6, lane = tid & 63;
    const int mi = wv & 1, ks = wv >> 1;
    const int m16 = lane & 15, kb = lane >> 4;
    const int klane = kb * 8;
    const int arow = bg * 32 + mi * 16 + m16;                 // global batch row for A-frag
    const unsigned short* bw0 = &BW[m16][klane];              // B-frag col ni=0
    const unsigned short* bw1 = &BW[16 + m16][klane];         // B-frag col ni=1

    __syncthreads();   // BW + biass + ldsflag ready

    for (int t = 0; t < T_LEN; ++t) {
        const unsigned short* hcur = hbuf + (size_t)(t & 1) * (BATCH * HID);
        unsigned short* hnxt = hbuf + (size_t)((t + 1) & 1) * (BATCH * HID);

        // ---- x-part (k in [ks*256, ks*256+256)): independent of h_t, before the wait
        f32x4 acc0 = {0.f, 0.f, 0.f, 0.f};
        f32x4 acc1 = {0.f, 0.f, 0.f, 0.f};
        const unsigned short* xa = x_tbd + ((size_t)t * BATCH + arow) * DIN + ks * 256 + klane;
#pragma unroll
        for (int j = 0; j < 8; ++j) {
            short8 af = *reinterpret_cast<const short8*>(xa + j * 32);
            short8 b0 = *reinterpret_cast<const short8*>(bw0 + ks * 256 + j * 32);
            short8 b1 = *reinterpret_cast<const short8*>(bw1 + ks * 256 + j * 32);
            acc0 = __builtin_amdgcn_mfma_f32_16x16x32_bf16(af, b0, acc0, 0, 0, 0);
            acc1 = __builtin_amdgcn_mfma_f32_16x16x32_bf16(af, b1, acc1, 0, 0, 0);
        }

        // ---- slot barrier: wave0 polls all 256 slots, releases siblings via LDS flag
        if (wv == 0) {
            const unsigned int tgt = (unsigned int)t;
            const unsigned long long* sp = (const unsigned long long*)slots + lane * 2;
            for (;;) {
                unsigned long long a = __hip_atomic_load(sp, __ATOMIC_RELAXED, __HIP_MEMORY_SCOPE_AGENT);
                unsigned long long d = __hip_atomic_load(sp + 1, __ATOMIC_RELAXED, __HIP_MEMORY_SCOPE_AGENT);
                int ok = ((unsigned int)a >= tgt) & ((unsigned int)(a >> 32) >= tgt) &
                         ((unsigned int)d >= tgt) & ((unsigned int)(d >> 32) >= tgt);
                if (__all(ok)) break;
                __builtin_amdgcn_s_sleep(2);
            }
            asm volatile("" ::: "memory");
            if (lane == 0)
                __hip_atomic_store(&ldsflag, (unsigned int)t, __ATOMIC_RELAXED, __HIP_MEMORY_SCOPE_WORKGROUP);
        } else {
            while (__hip_atomic_load(&ldsflag, __ATOMIC_RELAXED, __HIP_MEMORY_SCOPE_WORKGROUP) < (unsigned int)t)
                __builtin_amdgcn_s_sleep(1);
            asm volatile("" ::: "memory");
        }

        // ---- h-part (h-cols [ks*512, ks*512+512)): coherent loads from MALL
        const unsigned short* ha = hcur + (size_t)arow * HID + ks * 512 + klane;
#pragma unroll
        for (int j = 0; j < 16; ++j) {
            short8 af = ld_h_frag(ha + j * 32);
            short8 b0 = *reinterpret_cast<const short8*>(bw0 + DIN + ks * 512 + j * 32);
            short8 b1 = *reinterpret_cast<const short8*>(bw1 + DIN + ks * 512 + j * 32);
            acc0 = __builtin_amdgcn_mfma_f32_16x16x32_bf16(af, b0, acc0, 0, 0, 0);
            acc1 = __builtin_amdgcn_mfma_f32_16x16x32_bf16(af, b1, acc1, 0, 0, 0);
        }

        // C/D layout (m89): col = lane&15, row = (lane>>4)*4 + reg
        {
            const int grow = mi * 16 + kb * 4;
            gatesP[ks][grow + 0][m16] = acc0[0];
            gatesP[ks][grow + 1][m16] = acc0[1];
            gatesP[ks][grow + 2][m16] = acc0[2];
            gatesP[ks][grow + 3][m16] = acc0[3];
            gatesP[ks][grow + 0][16 + m16] = acc1[0];
            gatesP[ks][grow + 1][16 + m16] = acc1[1];
            gatesP[ks][grow + 2][16 + m16] = acc1[2];
            gatesP[ks][grow + 3][16 + m16] = acc1[3];
        }
        __syncthreads();   // (A) partials ready

        // ---- elementwise LSTM cell for this thread's (b, unit)
        {
            float gi = gatesP[0][m_loc][u]      + gatesP[1][m_loc][u]      + biass[u];
            float gf = gatesP[0][m_loc][8 + u]  + gatesP[1][m_loc][8 + u]  + biass[8 + u];
            float go = gatesP[0][m_loc][16 + u] + gatesP[1][m_loc][16 + u] + biass[16 + u];
            float gg = gatesP[0][m_loc][24 + u] + gatesP[1][m_loc][24 + u] + biass[24 + u];
            float si = 1.f / (1.f + __expf(-gi));
            float sf = 1.f / (1.f + __expf(-gf));
            float so = 1.f / (1.f + __expf(-go));
            float tg = 1.f - 2.f / (__expf(2.f * gg) + 1.f);
            float cc = sf * c + si * tg;
            float hc = so * (1.f - 2.f / (__expf(2.f * cc) + 1.f));
            if (t < len) { c = cc; h = hc; }
            out[((size_t)b * T_LEN + t) * HID + unit] = h;
            hsh[m_loc][u] = f2bf(h);       // carried value even when masked
        }
        __syncthreads();   // (B) hsh ready

        // ---- publish h_{t+1} (wave0): packed 8B agent-scope stores, then arrival slot
        if (wv == 0) {
            const int ml = lane >> 1, q = lane & 1;
            unsigned long long v =
                  (unsigned long long)hsh[ml][q * 4 + 0]
                | ((unsigned long long)hsh[ml][q * 4 + 1] << 16)
                | ((unsigned long long)hsh[ml][q * 4 + 2] << 32)
                | ((unsigned long long)hsh[ml][q * 4 + 3] << 48);
            const int bglob = bg * 32 + ml;
            __hip_atomic_store((unsigned long long*)(hnxt + (size_t)bglob * HID + ug * 8 + q * 4), v,
                               __ATOMIC_RELAXED, __HIP_MEMORY_SCOPE_AGENT);
            asm volatile("s_waitcnt vmcnt(0)" ::: "memory");   // h at coherence point
            if (lane == 0)
                __hip_atomic_store(&slots[wg], (unsigned int)(t + 1),
                                   __ATOMIC_RELAXED, __HIP_MEMORY_SCOPE_AGENT);
        }
    }

    // final states: out = [seq (B,T,H) | h_t (B,H) | c_t (B,H)]
    const size_t base = (size_t)BATCH * T_LEN * HID;
    out[base + (size_t)b * HID + unit] = h;
    out[base + (size_t)BATCH * HID + (size_t)b * HID + unit] = c;
}

extern "C" void kernel_launch(void* const* d_in, const int* in_sizes, int n_in,
                              void* d_out, int out_size, void* d_ws, size_t ws_size,
                              hipStream_t stream) {
    const float* x       = (const float*)d_in[0];
    const int*   lengths = (const int*)d_in[1];
    const float* Wx      = (const float*)d_in[2];
    const float* bx      = (const float*)d_in[3];
    const float* Wh      = (const float*)d_in[4];
    const float* bh      = (const float*)d_in[5];
    float* out = (float*)d_out;

    unsigned char* ws = (unsigned char*)d_ws;
    unsigned short* W_T   = (unsigned short*)(ws);                       // 12,582,912 B
    unsigned short* x_tbd = (unsigned short*)(ws + 12582912);            // 33,554,432 B
    unsigned short* hbuf  = (unsigned short*)(ws + 12582912 + 33554432); // 262,144 B
    float*          bias  = (float*)(ws + 46137344 + 262144);            // 16,384 B
    unsigned int*   slots = (unsigned int*)(ws + 46137344 + 262144 + 16384);

    wtrans_kernel<<<dim3(KTOT / 32, 4096 / 32), dim3(32, 8), 0, stream>>>(Wx, Wh, W_T);
    xtrans_kernel<<<16384, 256, 0, stream>>>(x, x_tbd);
    init_kernel<<<128, 256, 0, stream>>>(bx, bh, hbuf, bias, slots);

    void* args[] = {(void*)&x_tbd, (void*)&W_T, (void*)&bias, (void*)&lengths,
                    (void*)&hbuf, (void*)&out, (void*)&slots};
    hipLaunchCooperativeKernel((void*)lstm_kernel, dim3(256), dim3(256), args, 0, stream);
}